// Round 8
// baseline (41.381 us; speedup 1.0000x reference)
//
#include <hip/hip_runtime.h>

#define BATCH   256
#define NFEAT   20000
#define NVEC    (NFEAT / 4)
#define KSEL    256
#define NSAMP   8
#define CAP     2048

typedef unsigned long long u64;
typedef float __attribute__((ext_vector_type(4))) f32x4;

// Map float bits to unsigned key with same total order as float compare.
__device__ __forceinline__ unsigned fmap(float f) {
    unsigned u = __float_as_uint(f);
    return (u & 0x80000000u) ? ~u : (u | 0x80000000u);
}

// Generic top-down bin pick by wave 0 (rare refine path only).
__device__ __forceinline__ void select_bin_wave0(const unsigned* hist, int nbins, int w,
                                                 int* s_d, int* s_w, int lane) {
    for (int base = nbins - 1; base >= 0; base -= 64) {
        int bin = base - lane;
        unsigned c = (bin >= 0) ? hist[bin] : 0u;
        unsigned p = c;
#pragma unroll
        for (int off = 1; off < 64; off <<= 1) {
            unsigned t = __shfl_up(p, off);
            if (lane >= off) p += t;
        }
        unsigned long long m = __ballot(p >= (unsigned)w);
        if (m) {
            int l = __ffsll(m) - 1;
            if (lane == l) { *s_d = bin; *s_w = w - (int)(p - c); }
            return;
        }
        w -= (int)__shfl(p, 63);
    }
    if (lane == 0) { *s_d = 0; *s_w = 1; }
}

// Fast pick over exactly 64 entries (arr[63] = highest bin), wave 0 only.
__device__ __forceinline__ void pick64(const unsigned* arr, int w, int lane,
                                       int* s_idx, int* s_w) {
    unsigned c = arr[63 - lane];
    unsigned p = c;
#pragma unroll
    for (int off = 1; off < 64; off <<= 1) {
        unsigned t = __shfl_up(p, off);
        if (lane >= off) p += t;
    }
    unsigned long long m = __ballot(p >= (unsigned)w);
    if (m) {
        int l = __ffsll(m) - 1;
        if (lane == l) { *s_idx = 63 - l; *s_w = w - (int)(p - c); }
    } else if (lane == 0) { *s_idx = 0; *s_w = 1; }
}

// One 1024-thread block per row; row held in registers (20 keys/thread).
// Writes the exact top-K threshold as a 64-bit composite (key<<32 | ~idx):
// element selected iff composite >= thr (tie = lowest index, = jax.lax.top_k).
__global__ __launch_bounds__(1024) void topk_select(const float* __restrict__ logits,
                                                    u64* __restrict__ rowthr) {
    const int b = blockIdx.x, tid = threadIdx.x;
    const int lane = tid & 63, wave = tid >> 6;
    const float4* __restrict__ row4 = (const float4*)(logits + (size_t)b * NFEAT);

    __shared__ unsigned hist[4096];     // 16 KB
    __shared__ u64 cand[CAP];           // 16 KB
    __shared__ unsigned csum[64];
    __shared__ int s_d, s_w;
    __shared__ unsigned s_cnt;
    __shared__ u64 s_thr;
    __shared__ int s_run, s_cut, s_wc[16];

    // ---- Phase 1: issue 5 independent global loads early ----
    float4 v[5];
#pragma unroll
    for (int j = 0; j < 5; ++j) {
        const int i4 = tid + j * 1024;
        v[j] = row4[(i4 < NVEC) ? i4 : (NVEC - 1)];
    }
#pragma unroll
    for (int j = 0; j < 4; ++j) hist[tid + j * 1024] = 0;
    __syncthreads();

    unsigned kk[5][4];
#pragma unroll
    for (int j = 0; j < 5; ++j) {
        kk[j][0] = fmap(v[j].x); kk[j][1] = fmap(v[j].y);
        kk[j][2] = fmap(v[j].z); kk[j][3] = fmap(v[j].w);
    }
#pragma unroll
    for (int j = 0; j < 4; ++j) {
#pragma unroll
        for (int e = 0; e < 4; ++e) atomicAdd(&hist[kk[j][e] >> 20], 1u);
    }
    if (tid + 4096 < NVEC) {
#pragma unroll
        for (int e = 0; e < 4; ++e) atomicAdd(&hist[kk[4][e] >> 20], 1u);
    }
    __syncthreads();

    // ---- Phase 2: hierarchical threshold-bin pick ----
    unsigned keypref; int w;
    {
#pragma unroll
        for (int j = 0; j < 4; ++j) {
            const int c = wave * 4 + j;
            unsigned x = hist[c * 64 + lane];
#pragma unroll
            for (int off = 32; off; off >>= 1) x += __shfl_down(x, off);
            if (lane == 0) csum[c] = x;
        }
        __syncthreads();
        if (wave == 0) pick64(csum, KSEL, lane, &s_d, &s_w);
        __syncthreads();
        const int chunk = s_d; const int w0 = s_w;
        if (wave == 0) pick64(&hist[chunk * 64], w0, lane, &s_d, &s_w);
        if (tid == 0) s_cnt = 0;
        __syncthreads();
        keypref = (unsigned)(chunk * 64 + s_d);
        w = s_w;
    }
    int shift = 20;

    // ---- Phase 3: gather candidate composites from registers ----
    unsigned C;
    for (;;) {
#pragma unroll
        for (int j = 0; j < 5; ++j) {
            const int i4 = tid + j * 1024;
            if (i4 < NVEC) {
#pragma unroll
                for (int e = 0; e < 4; ++e) {
                    const unsigned k = kk[j][e];
                    if ((k >> shift) == keypref) {
                        unsigned p = atomicAdd(&s_cnt, 1u);
                        if (p < CAP) cand[p] = ((u64)k << 32) | (unsigned)~(4 * i4 + e);
                    }
                }
            }
        }
        __syncthreads();
        C = s_cnt;
        if (C <= CAP || shift == 0) break;

        // rare: refine key prefix from reg keys until candidate set fits
        const int nb = (shift >= 12) ? 12 : shift;
        const int nsh = shift - nb;
        for (int i = tid; i < (1 << nb); i += 1024) hist[i] = 0;
        __syncthreads();
#pragma unroll
        for (int j = 0; j < 5; ++j) {
            const int i4 = tid + j * 1024;
            if (i4 < NVEC) {
#pragma unroll
                for (int e = 0; e < 4; ++e) {
                    const unsigned k = kk[j][e];
                    if ((k >> shift) == keypref)
                        atomicAdd(&hist[(k >> nsh) & ((1u << nb) - 1u)], 1u);
                }
            }
        }
        __syncthreads();
        if (wave == 0) select_bin_wave0(hist, 1 << nb, w, &s_d, &s_w, lane);
        if (tid == 0) s_cnt = 0;
        __syncthreads();
        keypref = (keypref << nb) | (unsigned)s_d;
        w = s_w;
        shift = nsh;
    }

    // ---- Phase 4: resolve exact threshold ----
    if (C <= CAP) {
        // ranking select: the w-th largest has exactly w-1 greater (all distinct)
        for (int i = tid; i < (int)C; i += 1024) {
            const u64 ci = cand[i];
            int cgt = 0;
            for (int j = 0; j < (int)C; ++j) cgt += (cand[j] > ci) ? 1 : 0;
            if (cgt == w - 1) s_thr = ci;
        }
        __syncthreads();
    } else {
        // unreachable in practice: shift==0 with >CAP exact-duplicate keys.
        if (tid == 0) { s_run = 0; s_cut = 0; }
        __syncthreads();
#pragma unroll 1
        for (int j = 0; j < 5; ++j) {
            const int i4 = tid + j * 1024;
            bool eq[4];
            int cnt4 = 0;
#pragma unroll
            for (int e = 0; e < 4; ++e) {
                eq[e] = (i4 < NVEC) && (kk[j][e] == keypref);
                cnt4 += eq[e] ? 1 : 0;
            }
            unsigned p = (unsigned)cnt4;
#pragma unroll
            for (int off = 1; off < 64; off <<= 1) {
                unsigned t = __shfl_up(p, off);
                if (lane >= off) p += t;
            }
            const unsigned excl = p - (unsigned)cnt4;
            if (lane == 63) s_wc[wave] = (int)p;
            __syncthreads();
            int off0 = s_run + (int)excl;
            for (int x = 0; x < wave; ++x) off0 += s_wc[x];
#pragma unroll
            for (int e = 0; e < 4; ++e) {
                if (eq[e]) { if (off0 == w - 1) s_cut = 4 * i4 + e; ++off0; }
            }
            __syncthreads();
            if (tid == 0) { int t = 0; for (int x = 0; x < 16; ++x) t += s_wc[x]; s_run += t; }
            __syncthreads();
            if (s_run >= w) break;
        }
        if (tid == 0) s_thr = ((u64)keypref << 32) | (unsigned)~s_cut;
        __syncthreads();
    }

    if (tid == 0) rowthr[b] = s_thr;
}

// Wide-grid writer (proven ~11 us): each thread reads one float4 of logits,
// computes 4 mask values, writes to all 8 sample slices.
__global__ __launch_bounds__(256) void write_out(const float* __restrict__ logits,
                                                 const u64* __restrict__ rowthr,
                                                 float* __restrict__ out) {
    const int b = blockIdx.y;
    const int q = blockIdx.x * 256 + threadIdx.x;   // index over N/4
    if (q >= NVEC) return;

    const u64 thr = rowthr[b];
    const unsigned thr_k = (unsigned)(thr >> 32);
    const unsigned thr_l = (unsigned)thr;
    const int n = q * 4;
    const float4 v = *reinterpret_cast<const float4*>(logits + (size_t)b * NFEAT + n);

    f32x4 m;
    {
        const float* vf = &v.x;
#pragma unroll
        for (int j = 0; j < 4; ++j) {
            const unsigned k = fmap(vf[j]);
            const bool sel = (k > thr_k) || (k == thr_k && (unsigned)~(n + j) >= thr_l);
            m[j] = sel ? 1.0f : 0.0f;
        }
    }

#pragma unroll
    for (int s = 0; s < NSAMP; ++s) {
        *reinterpret_cast<f32x4*>(out + ((size_t)s * BATCH + b) * NFEAT + n) = m;
    }
}

extern "C" void kernel_launch(void* const* d_in, const int* in_sizes, int n_in,
                              void* d_out, int out_size, void* d_ws, size_t ws_size,
                              hipStream_t stream) {
    const float* logits = (const float*)d_in[0];
    float* out = (float*)d_out;
    u64* rowthr = (u64*)d_ws;   // 256 * 8 B = 2 KB

    topk_select<<<BATCH, 1024, 0, stream>>>(logits, rowthr);

    dim3 grid((NVEC + 255) / 256, BATCH);
    write_out<<<grid, 256, 0, stream>>>(logits, rowthr, out);
}